// Round 3
// baseline (1240.153 us; speedup 1.0000x reference)
//
#include <hip/hip_runtime.h>
#include <hip/hip_bf16.h>
#include <stdint.h>

// JointAttention: B=1, L=512(txt), N=4096(img), HID=1536, H=12, D=128
// Round 3: barrier-free S^T-orientation flash attention (direct-global K/V^T
// frags, per-wave LDS P-stash only); swapped-operand gemms so epilogues are
// packed b64 stores (rope pairs in-register); V written transposed.
// ws (bf16 elems): qb[0) kb[7077888) vbT[14155776) ob[21233664) -> 56.6 MB.

typedef __attribute__((ext_vector_type(8))) short short8;
typedef __attribute__((ext_vector_type(4))) float floatx4;
typedef __attribute__((ext_vector_type(4))) unsigned short ushort4v;

#define DEV __device__ __forceinline__

DEV float bf2f(uint16_t s) {
  union { uint32_t u; float f; } v;
  v.u = (uint32_t)s << 16;
  return v.f;
}
DEV uint16_t f2bf(float f) {
  __hip_bfloat16 h = __float2bfloat16(f);
  return __builtin_bit_cast(uint16_t, h);
}

DEV bool detect_bf16(const void* p) {
  const uint16_t* u = (const uint16_t*)p;
  int sane = 0;
  for (int i = 0; i < 64; ++i) {
    int e = (u[2 * i] >> 7) & 0xFF;
    sane += (e > 90 && e < 145) ? 1 : 0;
  }
  return sane >= 40;
}

DEV short8 load8(const void* base, long idx, bool bf) {
  if (bf) return *(const short8*)((const uint16_t*)base + idx);
  const floatx4* f = (const floatx4*)((const float*)base + idx);
  floatx4 a = f[0], b = f[1];
  short8 r;
  r[0] = (short)f2bf(a[0]); r[1] = (short)f2bf(a[1]);
  r[2] = (short)f2bf(a[2]); r[3] = (short)f2bf(a[3]);
  r[4] = (short)f2bf(b[0]); r[5] = (short)f2bf(b[1]);
  r[6] = (short)f2bf(b[2]); r[7] = (short)f2bf(b[3]);
  return r;
}

DEV void load4f(const void* base, long idx, bool bf, float& a, float& b,
                float& c, float& d) {
  if (bf) {
    ushort4v u = *(const ushort4v*)((const uint16_t*)base + idx);
    a = bf2f(u[0]); b = bf2f(u[1]); c = bf2f(u[2]); d = bf2f(u[3]);
  } else {
    floatx4 f = *(const floatx4*)((const float*)base + idx);
    a = f[0]; b = f[1]; c = f[2]; d = f[3];
  }
}

// ---------------------------------------------------------------------------
// acc[4][4] of A[M,K]*B[N,K]^T (both K-major). C row = bm-side (A operand),
// col = bn-side (B operand). 128x128 tile, BK=32, register staging + XOR
// chunk swizzle. Verified correct in round 2.
DEV void gemm_core(const void* A, const void* B, bool abf, bool bbf, long bm,
                   long bn, int K, uint16_t* sA, uint16_t* sB,
                   floatx4 (&acc)[4][4]) {
  const int t = threadIdx.x;
  const int lane = t & 63, wave = t >> 6, l16 = lane & 15, quad = lane >> 4;
  const int srow = t >> 2, c = t & 3, g = c ^ (srow & 3);
  const int wm = (wave >> 1) * 64, wn = (wave & 1) * 64;
  const int fsl = (quad ^ (l16 & 3)) * 8;
  for (int k0 = 0; k0 < K; k0 += 32) {
    short8 a0 = load8(A, (bm + srow) * (long)K + k0 + g * 8, abf);
    short8 a1 = load8(A, (bm + 64 + srow) * (long)K + k0 + g * 8, abf);
    short8 b0 = load8(B, (bn + srow) * (long)K + k0 + g * 8, bbf);
    short8 b1 = load8(B, (bn + 64 + srow) * (long)K + k0 + g * 8, bbf);
    __syncthreads();
    *(short8*)(sA + srow * 32 + c * 8) = a0;
    *(short8*)(sA + (64 + srow) * 32 + c * 8) = a1;
    *(short8*)(sB + srow * 32 + c * 8) = b0;
    *(short8*)(sB + (64 + srow) * 32 + c * 8) = b1;
    __syncthreads();
    short8 af[4], bfr[4];
#pragma unroll
    for (int i = 0; i < 4; ++i) {
      af[i] = *(const short8*)(sA + (wm + i * 16 + l16) * 32 + fsl);
      bfr[i] = *(const short8*)(sB + (wn + i * 16 + l16) * 32 + fsl);
    }
#pragma unroll
    for (int i = 0; i < 4; ++i)
#pragma unroll
      for (int j = 0; j < 4; ++j)
        acc[i][j] = __builtin_amdgcn_mfma_f32_16x16x32_bf16(af[i], bfr[j],
                                                            acc[i][j], 0, 0, 0);
  }
}

// ---------------------------------------------------------------------------
// Q/K projection, SWAPPED orientation: A = W (rows = features), B = X (rows =
// s). C row = feature (4 consecutive d per lane -> packed b64 into [h][s][d]),
// col = s. Rope pairs are in-register.
__global__ __launch_bounds__(256, 2) void qk_gemm(
    const void* X, const void* W, const void* rope, const void* det,
    uint16_t* qb, uint16_t* kb, int s_base) {
  __shared__ uint16_t sA[128 * 32], sB[128 * 32];
  const bool bf = detect_bf16(det);
  const long bm = (long)blockIdx.y * 128, bn = (long)blockIdx.x * 128;
  floatx4 acc[4][4] = {};
  gemm_core(W, X, bf, bf, bm, bn, 1536, sA, sB, acc);

  const int t = threadIdx.x, lane = t & 63, wave = t >> 6;
  const int l16 = lane & 15, quad = lane >> 4;
  const int wm = (wave >> 1) * 64, wn = (wave & 1) * 64;
  const int th = blockIdx.y, tt = th / 12, hh = th - tt * 12;
  uint16_t* dst = tt == 0 ? qb : kb;
  const bool do_rope = (s_base != 0);
#pragma unroll
  for (int i = 0; i < 4; ++i) {
    const int dbase = wm + i * 16 + quad * 4;  // d in [0,128), mult of 4
#pragma unroll
    for (int j = 0; j < 4; ++j) {
      const long s_g = bn + wn + j * 16 + l16;  // row within this input
      float v0 = acc[i][j][0], v1 = acc[i][j][1];
      float v2 = acc[i][j][2], v3 = acc[i][j][3];
      if (do_rope) {
        float c0, s0, c1, s1;
        load4f(rope, s_g * 128 + dbase, bf, c0, s0, c1, s1);
        float t0 = v0 * c0 - v1 * s0, t1 = v1 * c0 + v0 * s0;
        float t2 = v2 * c1 - v3 * s1, t3 = v3 * c1 + v2 * s1;
        v0 = t0; v1 = t1; v2 = t2; v3 = t3;
      }
      ushort4v pk;
      pk[0] = f2bf(v0); pk[1] = f2bf(v1); pk[2] = f2bf(v2); pk[3] = f2bf(v3);
      *(ushort4v*)(dst + ((long)hh * 4608 + s_base + s_g) * 128 + dbase) = pk;
    }
  }
}

// ---------------------------------------------------------------------------
// V projection, ORIGINAL orientation: A = X (rows = s), B = W rows 3072+
// (v-features). C row = s (4 consecutive per lane -> b64 into V^T[h][d][s]).
__global__ __launch_bounds__(256, 2) void v_gemm(
    const void* X, const void* W, const void* det, uint16_t* vbT, int s_base) {
  __shared__ uint16_t sA[128 * 32], sB[128 * 32];
  const bool bf = detect_bf16(det);
  const long bm = (long)blockIdx.y * 128, bn = (long)blockIdx.x * 128;
  floatx4 acc[4][4] = {};
  gemm_core(X, W, bf, bf, bm, bn + 3072, 1536, sA, sB, acc);

  const int t = threadIdx.x, lane = t & 63, wave = t >> 6;
  const int l16 = lane & 15, quad = lane >> 4;
  const int wm = (wave >> 1) * 64, wn = (wave & 1) * 64;
#pragma unroll
  for (int i = 0; i < 4; ++i) {
    const long s0v = bm + wm + i * 16 + quad * 4;  // s within input, mult of 4
#pragma unroll
    for (int j = 0; j < 4; ++j) {
      const int feat = bn + wn + j * 16 + l16;  // [0,1536)
      const int hh = feat >> 7, dd = feat & 127;
      ushort4v pk;
      pk[0] = f2bf(acc[i][j][0]); pk[1] = f2bf(acc[i][j][1]);
      pk[2] = f2bf(acc[i][j][2]); pk[3] = f2bf(acc[i][j][3]);
      *(ushort4v*)(vbT + ((long)hh * 128 + dd) * 4608 + s_base + s0v) = pk;
    }
  }
}

// ---------------------------------------------------------------------------
// Out projection, SWAPPED orientation: A = W_out (rows = out-features),
// B = ob (rows = s). C row = feature -> packed stores into d_out.
__global__ __launch_bounds__(256, 2) void out_gemm(
    const void* Wout, const uint16_t* ob, const void* det, void* out,
    long row_off) {
  __shared__ uint16_t sA[128 * 32], sB[128 * 32];
  const bool bf = detect_bf16(det);
  const long bm = (long)blockIdx.y * 128, bn = (long)blockIdx.x * 128;
  floatx4 acc[4][4] = {};
  gemm_core(Wout, ob, bf, true, bm, bn, 1536, sA, sB, acc);

  const int t = threadIdx.x, lane = t & 63, wave = t >> 6;
  const int l16 = lane & 15, quad = lane >> 4;
  const int wm = (wave >> 1) * 64, wn = (wave & 1) * 64;
#pragma unroll
  for (int i = 0; i < 4; ++i) {
    const int f0 = bm + wm + i * 16 + quad * 4;  // out-feature, mult of 4
#pragma unroll
    for (int j = 0; j < 4; ++j) {
      const long s_g = bn + wn + j * 16 + l16;
      const long idx = (row_off + s_g) * 1536 + f0;
      if (bf) {
        ushort4v pk;
        pk[0] = f2bf(acc[i][j][0]); pk[1] = f2bf(acc[i][j][1]);
        pk[2] = f2bf(acc[i][j][2]); pk[3] = f2bf(acc[i][j][3]);
        *(ushort4v*)((uint16_t*)out + idx) = pk;
      } else {
        *(floatx4*)((float*)out + idx) = acc[i][j];
      }
    }
  }
}

// ---------------------------------------------------------------------------
// Flash attention, barrier-free. Block = 128 threads = 2 waves; each wave owns
// 32 q-rows (2 subtiles of 16). S^T orientation: A = K (global b128 frags),
// B = Q (loaded once). Lane owns q-column l16: softmax in-lane + 2 shfls.
// P stash: per-wave LDS, b64 writes (kr ^ (l16&3) swizzle), b128 reads.
// PV: A = P, B = V^T rows direct from global. No __syncthreads anywhere.
__global__ __launch_bounds__(128, 2) void attn(
    const uint16_t* __restrict__ qb, const uint16_t* __restrict__ kb,
    const uint16_t* __restrict__ vbT, uint16_t* __restrict__ ob) {
  __shared__ uint16_t sP[2][2][16 * 64];  // [wave][sub][q][key]

  const int t = threadIdx.x;
  const int lane = t & 63, wave = t >> 6;
  const int l16 = lane & 15, quad = lane >> 4;
  const int h = blockIdx.y;
  const int q0 = blockIdx.x * 64 + wave * 32;

  const uint16_t* Qh = qb + (long)h * 4608 * 128;
  const uint16_t* Kh = kb + (long)h * 4608 * 128;
  const uint16_t* Vt = vbT + (long)h * 128 * 4608;

  short8 bq[2][4];
#pragma unroll
  for (int sub = 0; sub < 2; ++sub)
#pragma unroll
    for (int dk = 0; dk < 4; ++dk)
      bq[sub][dk] = *(const short8*)(Qh + (long)(q0 + sub * 16 + l16) * 128 +
                                     dk * 32 + quad * 8);

  float m_i[2] = {-1e30f, -1e30f};
  float l_i[2] = {0.f, 0.f};
  floatx4 accO[2][8] = {};

  char* pw = (char*)&sP[wave][0][0];
  const int swz = l16 & 3;

  for (int kt = 0; kt < 72; ++kt) {
    const long key0 = (long)kt * 64;
    floatx4 sc[2][4] = {};
#pragma unroll
    for (int kr = 0; kr < 4; ++kr) {
      short8 ak[4];
#pragma unroll
      for (int dk = 0; dk < 4; ++dk)
        ak[dk] = *(const short8*)(Kh + (key0 + kr * 16 + l16) * 128 + dk * 32 +
                                  quad * 8);
#pragma unroll
      for (int dk = 0; dk < 4; ++dk) {
        sc[0][kr] = __builtin_amdgcn_mfma_f32_16x16x32_bf16(ak[dk], bq[0][dk],
                                                            sc[0][kr], 0, 0, 0);
        sc[1][kr] = __builtin_amdgcn_mfma_f32_16x16x32_bf16(ak[dk], bq[1][dk],
                                                            sc[1][kr], 0, 0, 0);
      }
    }

    float alpha_s[2];
#pragma unroll
    for (int sub = 0; sub < 2; ++sub) {
      float mx = -1e30f;
#pragma unroll
      for (int kr = 0; kr < 4; ++kr)
#pragma unroll
        for (int r = 0; r < 4; ++r) {
          float s = sc[sub][kr][r] * 0.08838834764831845f;
          sc[sub][kr][r] = s;
          mx = fmaxf(mx, s);
        }
      mx = fmaxf(mx, __shfl_xor(mx, 16));
      mx = fmaxf(mx, __shfl_xor(mx, 32));
      const float mn = fmaxf(m_i[sub], mx);
      alpha_s[sub] = __expf(m_i[sub] - mn);
      m_i[sub] = mn;
      float lsum = 0.f;
#pragma unroll
      for (int kr = 0; kr < 4; ++kr) {
        ushort4v pk;
#pragma unroll
        for (int r = 0; r < 4; ++r) {
          float p = __expf(sc[sub][kr][r] - mn);
          lsum += p;
          pk[r] = f2bf(p);
        }
        *(ushort4v*)(pw + sub * 2048 + l16 * 128 + ((kr ^ swz) * 32) +
                     quad * 8) = pk;
      }
      lsum += __shfl_xor(lsum, 16);
      lsum += __shfl_xor(lsum, 32);
      l_i[sub] = l_i[sub] * alpha_s[sub] + lsum;
    }

    asm volatile("s_waitcnt lgkmcnt(0)" ::: "memory");

#pragma unroll
    for (int sub = 0; sub < 2; ++sub)
#pragma unroll
      for (int r = 0; r < 4; ++r) {
        const float ar = __shfl(alpha_s[sub], (lane & 48) | (quad * 4 + r));
#pragma unroll
        for (int vt = 0; vt < 8; ++vt) accO[sub][vt][r] *= ar;
      }

#pragma unroll
    for (int c = 0; c < 2; ++c) {
      const int rdoff =
          l16 * 128 + (((2 * c + (quad >> 1)) ^ swz) * 32) + (quad & 1) * 16;
      short8 pf0 = *(const short8*)(pw + rdoff);
      short8 pf1 = *(const short8*)(pw + 2048 + rdoff);
#pragma unroll
      for (int vt = 0; vt < 8; ++vt) {
        short8 bv = *(const short8*)(Vt + (long)(vt * 16 + l16) * 4608 + key0 +
                                     c * 32 + quad * 8);
        accO[0][vt] = __builtin_amdgcn_mfma_f32_16x16x32_bf16(
            pf0, bv, accO[0][vt], 0, 0, 0);
        accO[1][vt] = __builtin_amdgcn_mfma_f32_16x16x32_bf16(
            pf1, bv, accO[1][vt], 0, 0, 0);
      }
    }
  }

#pragma unroll
  for (int sub = 0; sub < 2; ++sub)
#pragma unroll
    for (int r = 0; r < 4; ++r) {
      const float lr = __shfl(l_i[sub], (lane & 48) | (quad * 4 + r));
      const float inv = 1.f / lr;
      const long row = q0 + sub * 16 + quad * 4 + r;
#pragma unroll
      for (int vt = 0; vt < 8; ++vt)
        ob[row * 1536 + h * 128 + vt * 16 + l16] =
            f2bf(accO[sub][vt][r] * inv);
    }
}

// ---------------------------------------------------------------------------
extern "C" void kernel_launch(void* const* d_in, const int* in_sizes, int n_in,
                              void* d_out, int out_size, void* d_ws,
                              size_t ws_size, hipStream_t stream) {
  const void* txt = d_in[0];
  const void* img = d_in[1];
  const void* rope = d_in[2];
  const void* Wtq = d_in[3];
  const void* Wiq = d_in[4];
  const void* Wto = d_in[5];
  const void* Wio = d_in[6];

  uint16_t* ws = (uint16_t*)d_ws;
  uint16_t* qb = ws;                   // [12][4608][128]
  uint16_t* kb = ws + 7077888;         // [12][4608][128]
  uint16_t* vbT = ws + 14155776;       // [12][128][4608]
  uint16_t* ob = ws + 21233664;        // [4608][1536]

  qk_gemm<<<dim3(4, 24), 256, 0, stream>>>(txt, Wtq, rope, txt, qb, kb, 0);
  qk_gemm<<<dim3(32, 24), 256, 0, stream>>>(img, Wiq, rope, txt, qb, kb, 512);

  v_gemm<<<dim3(12, 4), 256, 0, stream>>>(txt, Wtq, txt, vbT, 0);
  v_gemm<<<dim3(12, 32), 256, 0, stream>>>(img, Wiq, txt, vbT, 512);

  attn<<<dim3(72, 12), 128, 0, stream>>>(qb, kb, vbT, ob);

  out_gemm<<<dim3(4, 12), 256, 0, stream>>>(Wto, ob, txt, d_out, 0);
  out_gemm<<<dim3(32, 12), 256, 0, stream>>>(Wio, ob + (long)512 * 1536, txt,
                                             d_out, 512);
}